// Round 1
// baseline (189.070 us; speedup 1.0000x reference)
//
#include <hip/hip_runtime.h>
#include <math.h>

#define NBATCH 64
#define NPG 1024
#define NFEAT 8
#define NTOT (NBATCH * NPG)

static constexpr float MIN_DIST = 2.9f;
static constexpr float MD2 = MIN_DIST * MIN_DIST;

// ws float layout:
// [0] recon_sum  [1] elec_sum  [2] elec_cnt  [3] collapse_sum
// [16 + b*16 + q]: q=0..2 pdim xyz, 3..5 odim xyz, 6 zpmin, 7 zpr, 8 zpsum, 9 v

__device__ __forceinline__ float waveSum(float v) {
#pragma unroll
  for (int o = 32; o > 0; o >>= 1) v += __shfl_down(v, o, 64);
  return v;
}

__global__ __launch_bounds__(256) void stats_kernel(
    const float* __restrict__ pred, const float* __restrict__ tru,
    const float* __restrict__ orig, const float* __restrict__ feat,
    float* __restrict__ ws) {
  __shared__ float sh[14][256];
  const int b = blockIdx.x;
  const int tid = threadIdx.x;
  const float* pb = pred + (size_t)b * NPG * 3;
  const float* tb = tru  + (size_t)b * NPG * 3;
  const float* ob = orig + (size_t)b * NPG * 3;

  float pmn[3] = { INFINITY,  INFINITY,  INFINITY};
  float pmx[3] = {-INFINITY, -INFINITY, -INFINITY};
  float omn[3] = { INFINITY,  INFINITY,  INFINITY};
  float omx[3] = {-INFINITY, -INFINITY, -INFINITY};
  float recon = 0.f, zpsum = 0.f;
  for (int i = tid; i < NPG; i += 256) {
    float p0 = pb[i*3+0], p1 = pb[i*3+1], p2 = pb[i*3+2];
    float t0 = tb[i*3+0], t1 = tb[i*3+1], t2 = tb[i*3+2];
    float o0 = ob[i*3+0], o1 = ob[i*3+1], o2 = ob[i*3+2];
    pmn[0] = fminf(pmn[0], p0); pmx[0] = fmaxf(pmx[0], p0);
    pmn[1] = fminf(pmn[1], p1); pmx[1] = fmaxf(pmx[1], p1);
    pmn[2] = fminf(pmn[2], p2); pmx[2] = fmaxf(pmx[2], p2);
    omn[0] = fminf(omn[0], o0); omx[0] = fmaxf(omx[0], o0);
    omn[1] = fminf(omn[1], o1); omx[1] = fmaxf(omx[1], o1);
    omn[2] = fminf(omn[2], o2); omx[2] = fmaxf(omx[2], o2);
    float d0 = p0 - t0, d1 = p1 - t1, d2 = p2 - t2;
    recon += d0*d0 + d1*d1 + d2*d2;
    zpsum += p2;
  }
#pragma unroll
  for (int q = 0; q < 3; q++) {
    sh[q    ][tid] = pmn[q];
    sh[q + 3][tid] = pmx[q];
    sh[q + 6][tid] = omn[q];
    sh[q + 9][tid] = omx[q];
  }
  sh[12][tid] = recon;
  sh[13][tid] = zpsum;
  for (int s = 128; s > 0; s >>= 1) {
    __syncthreads();
    if (tid < s) {
#pragma unroll
      for (int q = 0; q < 3; q++) {
        sh[q    ][tid] = fminf(sh[q    ][tid], sh[q    ][tid + s]);
        sh[q + 3][tid] = fmaxf(sh[q + 3][tid], sh[q + 3][tid + s]);
        sh[q + 6][tid] = fminf(sh[q + 6][tid], sh[q + 6][tid + s]);
        sh[q + 9][tid] = fmaxf(sh[q + 9][tid], sh[q + 9][tid + s]);
      }
      sh[12][tid] += sh[12][tid + s];
      sh[13][tid] += sh[13][tid + s];
    }
  }
  __syncthreads();
  // snapshot phase-1 results into registers (broadcast reads)
  float res[14];
#pragma unroll
  for (int q = 0; q < 14; q++) res[q] = sh[q][0];

  const float ozmin = res[8], ozmax = res[11];
  const float zr = ozmax - ozmin;
  const float lo = ozmin + 0.15f * zr;
  const float hi = ozmax - 0.15f * zr;

  float cnt = 0.f, elec = 0.f;
  for (int i = tid; i < NPG; i += 256) {
    float oz = ob[i*3+2];
    if (oz <= lo || oz >= hi) {
      float p0 = pb[i*3+0], p1 = pb[i*3+1], p2 = pb[i*3+2];
      float o0 = ob[i*3+0], o1 = ob[i*3+1];
      float d0 = p0 - o0, d1 = p1 - o1, d2 = p2 - oz;
      cnt += 1.f;
      elec += d0*d0 + d1*d1 + d2*d2;
    }
  }
  __syncthreads();  // everyone has res[] in regs; safe to reuse sh
  sh[0][tid] = cnt;
  sh[1][tid] = elec;
  for (int s = 128; s > 0; s >>= 1) {
    __syncthreads();
    if (tid < s) {
      sh[0][tid] += sh[0][tid + s];
      sh[1][tid] += sh[1][tid + s];
    }
  }
  __syncthreads();
  if (tid == 0) {
    atomicAdd(&ws[0], res[12]);     // recon sum
    atomicAdd(&ws[1], sh[1][0]);    // elec sum
    atomicAdd(&ws[2], sh[0][0]);    // elec cnt
    float* o = ws + 16 + b * 16;
    o[0] = res[3]  - res[0];        // pdim x
    o[1] = res[4]  - res[1];        // pdim y
    o[2] = res[5]  - res[2];        // pdim z
    o[3] = res[9]  - res[6];        // odim x
    o[4] = res[10] - res[7];        // odim y
    o[5] = res[11] - res[8];        // odim z
    o[6] = res[2];                  // pred z min
    o[7] = res[5] - res[2];         // pred z range
    o[8] = res[13];                 // pred z sum
    o[9] = feat[(size_t)b * NPG * NFEAT + (NFEAT - 3)];  // v
  }
}

__global__ __launch_bounds__(256) void collapse_kernel(
    const float* __restrict__ pred, float* __restrict__ ws) {
  __shared__ float4 pts[NPG];
  __shared__ float sred[4];
  const int b = blockIdx.x >> 2;
  const int tid = threadIdx.x;
  const float* pb = pred + (size_t)b * NPG * 3;
  for (int k = tid; k < NPG; k += 256) {
    pts[k] = make_float4(pb[k*3+0], pb[k*3+1], pb[k*3+2], 0.f);
  }
  __syncthreads();
  const int i = ((blockIdx.x & 3) << 8) + tid;
  const float4 pi = pts[i];
  float acc = 0.f;
#pragma unroll 8
  for (int j = 0; j < NPG; j++) {
    float4 pj = pts[j];  // same-address broadcast across the wave: conflict-free
    float dx = pi.x - pj.x, dy = pi.y - pj.y, dz = pi.z - pj.z;
    float d2 = fmaf(dx, dx, fmaf(dy, dy, dz * dz));
    if (d2 < MD2) {
      float d = sqrtf(fmaxf(d2, 1e-12f));
      float t = MIN_DIST - d;
      acc += (j == i) ? 0.f : t * t;
    }
  }
  acc = waveSum(acc);
  const int lane = tid & 63, wid = tid >> 6;
  if (lane == 0) sred[wid] = acc;
  __syncthreads();
  if (tid == 0) {
    atomicAdd(&ws[3], sred[0] + sred[1] + sred[2] + sred[3]);
  }
}

__global__ __launch_bounds__(64) void final_kernel(
    const float* __restrict__ ws, float* __restrict__ out) {
  const int b = threadIdx.x;  // 0..63, one lane per batch
  const float* s = ws + 16 + b * 16;
  float pdx = s[0], pdy = s[1], pdz = s[2];
  float odx = s[3], ody = s[4], odz = s[5];
  float zpmin = s[6], zpr = s[7], zpsum = s[8], v = s[9];

  float rx = (pdx - odx) / (odx + 1e-8f);
  float ry = (pdy - ody) / (ody + 1e-8f);
  float rz = (pdz - odz) / (odz + 1e-8f);
  float xy_pen = fmaxf(rx - 0.02f, 0.f) + fmaxf(ry - 0.02f, 0.f);
  float z_pen = fmaxf(rz, 0.f);
  float vol = xy_pen + 2.f * z_pen;

  float zcom = zpsum * (1.f / NPG);
  float znorm = (zcom - zpmin) / (zpr + 1e-8f);
  float target = (v > 0.f) ? 0.6f : 0.4f;
  float d = znorm - target;
  float contrib = (fabsf(v) >= 1e-6f) ? d * d : 0.f;

  vol = waveSum(vol);
  contrib = waveSum(contrib);
  if (b == 0) {
    float recon = ws[0] / (float)(NTOT * 3);
    float volume = vol / (float)NBATCH;
    float electrode = ws[1] / (ws[2] * 3.f);
    float collapse = ws[3] / ((float)NBATCH * NPG * (NPG - 1));
    float field = contrib / (float)NBATCH;
    float total = 1.0f * recon + 10.0f * volume + 50.0f * electrode +
                  5.0f * collapse + 2.0f * field;
    out[0] = total;
    out[1] = recon;
    out[2] = volume;
    out[3] = electrode;
    out[4] = collapse;
    out[5] = field;
  }
}

extern "C" void kernel_launch(void* const* d_in, const int* in_sizes, int n_in,
                              void* d_out, int out_size, void* d_ws, size_t ws_size,
                              hipStream_t stream) {
  const float* pred = (const float*)d_in[0];
  const float* tru  = (const float*)d_in[1];
  const float* orig = (const float*)d_in[2];
  const float* feat = (const float*)d_in[3];
  // d_in[4] (batch_vector) is a regular repeat(arange) — not needed.
  float* ws  = (float*)d_ws;
  float* out = (float*)d_out;

  hipMemsetAsync(d_ws, 0, 4 * sizeof(float), stream);  // zero global accumulators
  stats_kernel<<<NBATCH, 256, 0, stream>>>(pred, tru, orig, feat, ws);
  collapse_kernel<<<NBATCH * 4, 256, 0, stream>>>(pred, ws);
  final_kernel<<<1, 64, 0, stream>>>(ws, out);
}

// Round 3
// 110.422 us; speedup vs baseline: 1.7123x; 1.7123x over previous
//
#include <hip/hip_runtime.h>
#include <math.h>

#define NBATCH 64
#define NPG 1024
#define NFEAT 8
#define NTOT (NBATCH * NPG)

// collapse tiling
#define TI 256                 // i-points per block (= blockDim)
#define TJ 128                 // j-points per block (staged in LDS)
#define NIC (NPG / TI)         // 4 i-chunks
#define NJC (NPG / TJ)         // 8 j-chunks
#define NCOLL (NBATCH * NIC * NJC)  // 2048 collapse blocks

static constexpr float MIN_DIST = 2.9f;

// ws float layout (all written before read; no zero-init needed):
//   [16 + b*16 + q]: q0..2 pdim xyz, 3..5 odim xyz, 6 zpmin, 7 zpr, 8 zpsum,
//                    9 v, 10 recon_b, 11 elec_b, 12 cnt_b
//   [4096 + k]: collapse partial of block k, k in [0, NCOLL)
#define WS_BATCH 16
#define WS_COLL 4096

__device__ __forceinline__ float waveSum(float v) {
#pragma unroll
  for (int o = 32; o > 0; o >>= 1) v += __shfl_down(v, o, 64);
  return v;
}

__global__ __launch_bounds__(256) void stats_kernel(
    const float* __restrict__ pred, const float* __restrict__ tru,
    const float* __restrict__ orig, const float* __restrict__ feat,
    float* __restrict__ ws) {
  __shared__ float sh[14][256];
  const int b = blockIdx.x;
  const int tid = threadIdx.x;
  const float* pb = pred + (size_t)b * NPG * 3;
  const float* tb = tru  + (size_t)b * NPG * 3;
  const float* ob = orig + (size_t)b * NPG * 3;

  float pmn[3] = { INFINITY,  INFINITY,  INFINITY};
  float pmx[3] = {-INFINITY, -INFINITY, -INFINITY};
  float omn[3] = { INFINITY,  INFINITY,  INFINITY};
  float omx[3] = {-INFINITY, -INFINITY, -INFINITY};
  float recon = 0.f, zpsum = 0.f;
  for (int i = tid; i < NPG; i += 256) {
    float p0 = pb[i*3+0], p1 = pb[i*3+1], p2 = pb[i*3+2];
    float t0 = tb[i*3+0], t1 = tb[i*3+1], t2 = tb[i*3+2];
    float o0 = ob[i*3+0], o1 = ob[i*3+1], o2 = ob[i*3+2];
    pmn[0] = fminf(pmn[0], p0); pmx[0] = fmaxf(pmx[0], p0);
    pmn[1] = fminf(pmn[1], p1); pmx[1] = fmaxf(pmx[1], p1);
    pmn[2] = fminf(pmn[2], p2); pmx[2] = fmaxf(pmx[2], p2);
    omn[0] = fminf(omn[0], o0); omx[0] = fmaxf(omx[0], o0);
    omn[1] = fminf(omn[1], o1); omx[1] = fmaxf(omx[1], o1);
    omn[2] = fminf(omn[2], o2); omx[2] = fmaxf(omx[2], o2);
    float d0 = p0 - t0, d1 = p1 - t1, d2 = p2 - t2;
    recon += d0*d0 + d1*d1 + d2*d2;
    zpsum += p2;
  }
#pragma unroll
  for (int q = 0; q < 3; q++) {
    sh[q    ][tid] = pmn[q];
    sh[q + 3][tid] = pmx[q];
    sh[q + 6][tid] = omn[q];
    sh[q + 9][tid] = omx[q];
  }
  sh[12][tid] = recon;
  sh[13][tid] = zpsum;
  for (int s = 128; s > 0; s >>= 1) {
    __syncthreads();
    if (tid < s) {
#pragma unroll
      for (int q = 0; q < 3; q++) {
        sh[q    ][tid] = fminf(sh[q    ][tid], sh[q    ][tid + s]);
        sh[q + 3][tid] = fmaxf(sh[q + 3][tid], sh[q + 3][tid + s]);
        sh[q + 6][tid] = fminf(sh[q + 6][tid], sh[q + 6][tid + s]);
        sh[q + 9][tid] = fmaxf(sh[q + 9][tid], sh[q + 9][tid + s]);
      }
      sh[12][tid] += sh[12][tid + s];
      sh[13][tid] += sh[13][tid + s];
    }
  }
  __syncthreads();
  float res[14];
#pragma unroll
  for (int q = 0; q < 14; q++) res[q] = sh[q][0];

  const float ozmin = res[8], ozmax = res[11];
  const float zr = ozmax - ozmin;
  const float lo = ozmin + 0.15f * zr;
  const float hi = ozmax - 0.15f * zr;

  float cnt = 0.f, elec = 0.f;
  for (int i = tid; i < NPG; i += 256) {
    float oz = ob[i*3+2];
    if (oz <= lo || oz >= hi) {
      float p0 = pb[i*3+0], p1 = pb[i*3+1], p2 = pb[i*3+2];
      float o0 = ob[i*3+0], o1 = ob[i*3+1];
      float d0 = p0 - o0, d1 = p1 - o1, d2 = p2 - oz;
      cnt += 1.f;
      elec += d0*d0 + d1*d1 + d2*d2;
    }
  }
  __syncthreads();  // res[] snapshotted in regs; safe to reuse sh
  sh[0][tid] = cnt;
  sh[1][tid] = elec;
  for (int s = 128; s > 0; s >>= 1) {
    __syncthreads();
    if (tid < s) {
      sh[0][tid] += sh[0][tid + s];
      sh[1][tid] += sh[1][tid + s];
    }
  }
  __syncthreads();
  if (tid == 0) {
    float* o = ws + WS_BATCH + b * 16;
    o[0]  = res[3]  - res[0];        // pdim x
    o[1]  = res[4]  - res[1];        // pdim y
    o[2]  = res[5]  - res[2];        // pdim z
    o[3]  = res[9]  - res[6];        // odim x
    o[4]  = res[10] - res[7];        // odim y
    o[5]  = res[11] - res[8];        // odim z
    o[6]  = res[2];                  // pred z min
    o[7]  = res[5] - res[2];         // pred z range
    o[8]  = res[13];                 // pred z sum
    o[9]  = feat[(size_t)b * NPG * NFEAT + (NFEAT - 3)];  // v
    o[10] = res[12];                 // recon partial
    o[11] = sh[1][0];                // elec partial
    o[12] = sh[0][0];                // cnt partial
  }
}

__global__ __launch_bounds__(256) void collapse_kernel(
    const float* __restrict__ pred, float* __restrict__ ws) {
  __shared__ float4 pts[TJ];
  __shared__ float sred[4];
  const int x = blockIdx.x;
  const int b = x / (NIC * NJC);
  const int chunk = x % (NIC * NJC);
  const int ic = chunk / NJC;
  const int jc = chunk % NJC;
  const int tid = threadIdx.x;
  const float* pb = pred + (size_t)b * NPG * 3;
  const int j0 = jc * TJ;

  if (tid < TJ) {
    int j = j0 + tid;
    pts[tid] = make_float4(pb[j*3+0], pb[j*3+1], pb[j*3+2], 0.f);
  }
  const int i = ic * TI + tid;
  const float px = pb[i*3+0], py = pb[i*3+1], pz = pb[i*3+2];
  __syncthreads();

  float acc = 0.f;
#pragma unroll 8
  for (int j = 0; j < TJ; j++) {
    float4 pj = pts[j];  // wave-uniform address: LDS broadcast, conflict-free
    float dx = px - pj.x, dy = py - pj.y, dz = pz - pj.z;
    float d2 = fmaf(dx, dx, fmaf(dy, dy, dz * dz));
    float d = sqrtf(fmaxf(d2, 1e-12f));
    float t = fmaxf(MIN_DIST - d, 0.f);
    acc = fmaf(t, t, acc);
  }
  // remove the self-pair (i==j) contribution with the exact same float ops
  if (i >= j0 && i < j0 + TJ) {
    float d = sqrtf(1e-12f);
    float t = fmaxf(MIN_DIST - d, 0.f);
    acc -= t * t;
  }

  acc = waveSum(acc);
  if ((tid & 63) == 0) sred[tid >> 6] = acc;
  __syncthreads();
  if (tid == 0) ws[WS_COLL + x] = sred[0] + sred[1] + sred[2] + sred[3];
}

__global__ __launch_bounds__(256) void final_kernel(
    const float* __restrict__ ws, float* __restrict__ out) {
  const int tid = threadIdx.x;
  __shared__ float shc[4];

  // reduce collapse partials (2048 values over 256 threads)
  float c = 0.f;
  for (int k = tid; k < NCOLL; k += 256) c += ws[WS_COLL + k];
  c = waveSum(c);
  if ((tid & 63) == 0) shc[tid >> 6] = c;
  __syncthreads();

  // per-batch terms: wave 0 only (threads 0..63 == lanes of wave 0)
  if (tid < 64) {
    const float* s = ws + WS_BATCH + tid * 16;
    float pdx = s[0], pdy = s[1], pdz = s[2];
    float odx = s[3], ody = s[4], odz = s[5];
    float zpmin = s[6], zpr = s[7], zpsum = s[8], v = s[9];

    float rx = (pdx - odx) / (odx + 1e-8f);
    float ry = (pdy - ody) / (ody + 1e-8f);
    float rz = (pdz - odz) / (odz + 1e-8f);
    float vol = fmaxf(rx - 0.02f, 0.f) + fmaxf(ry - 0.02f, 0.f) +
                2.f * fmaxf(rz, 0.f);

    float zcom = zpsum * (1.f / NPG);
    float znorm = (zcom - zpmin) / (zpr + 1e-8f);
    float target = (v > 0.f) ? 0.6f : 0.4f;
    float dd = znorm - target;
    float contrib = (fabsf(v) >= 1e-6f) ? dd * dd : 0.f;

    float recon = s[10], elec = s[11], cnt = s[12];

    vol = waveSum(vol);
    contrib = waveSum(contrib);
    recon = waveSum(recon);
    elec = waveSum(elec);
    cnt = waveSum(cnt);

    if (tid == 0) {
      float ctotal = shc[0] + shc[1] + shc[2] + shc[3];
      float o_recon = recon / (float)(NTOT * 3);
      float o_volume = vol / (float)NBATCH;
      float o_elec = elec / (cnt * 3.f);
      float o_coll = ctotal / ((float)NBATCH * NPG * (NPG - 1));
      float o_field = contrib / (float)NBATCH;
      float total = 1.0f * o_recon + 10.0f * o_volume + 50.0f * o_elec +
                    5.0f * o_coll + 2.0f * o_field;
      out[0] = total;
      out[1] = o_recon;
      out[2] = o_volume;
      out[3] = o_elec;
      out[4] = o_coll;
      out[5] = o_field;
    }
  }
}

extern "C" void kernel_launch(void* const* d_in, const int* in_sizes, int n_in,
                              void* d_out, int out_size, void* d_ws, size_t ws_size,
                              hipStream_t stream) {
  const float* pred = (const float*)d_in[0];
  const float* tru  = (const float*)d_in[1];
  const float* orig = (const float*)d_in[2];
  const float* feat = (const float*)d_in[3];
  float* ws  = (float*)d_ws;
  float* out = (float*)d_out;

  stats_kernel<<<NBATCH, 256, 0, stream>>>(pred, tru, orig, feat, ws);
  collapse_kernel<<<NCOLL, 256, 0, stream>>>(pred, ws);
  final_kernel<<<1, 256, 0, stream>>>(ws, out);
}

// Round 5
// 90.611 us; speedup vs baseline: 2.0866x; 1.2186x over previous
//
#include <hip/hip_runtime.h>
#include <math.h>

#define NB 64
#define NPG 1024
#define NFEAT 8
#define NTOT (NB * NPG)
#define TT 256                  // collapse tile edge (i and j)

static constexpr float MIN_DIST = 2.9f;

#if __has_builtin(__builtin_amdgcn_sqrtf)
#define FAST_SQRT(x) __builtin_amdgcn_sqrtf(x)   // raw v_sqrt_f32, ~1 ulp
#else
#define FAST_SQRT(x) sqrtf(x)
#endif

// ws float layout (every slot written before read; no zero-init needed):
//   WS_STATS + (b*4+q)*16 + j : per-quarter stats partials, j:
//        0..2 pmin, 3..5 pmax, 6..8 omin, 9..11 omax, 12 recon, 13 zpsum
//   WS_V   + b : node_features v per batch
//   WS_CNT + b : electrode count per batch
//   WS_ELE + b : electrode sum per batch
//   WS_COLL + x : collapse partial per block x (x < 1024)
// total 5312 floats = 21.2 KB (R3 proved >= 24.6 KB available)
#define WS_STATS 0
#define WS_V     4096
#define WS_CNT   4160
#define WS_ELE   4224
#define WS_COLL  4288

__device__ __forceinline__ float waveSum(float v) {
#pragma unroll
  for (int o = 32; o > 0; o >>= 1) v += __shfl_down(v, o, 64);
  return v;
}
__device__ __forceinline__ float waveMin(float v) {
#pragma unroll
  for (int o = 32; o > 0; o >>= 1) v = fminf(v, __shfl_down(v, o, 64));
  return v;
}
__device__ __forceinline__ float waveMax(float v) {
#pragma unroll
  for (int o = 32; o > 0; o >>= 1) v = fmaxf(v, __shfl_down(v, o, 64));
  return v;
}

// 256 blocks x 256 threads: block (b, q) reduces points [q*256, q*256+256)
// of batch b. Fully parallel (1 block/CU).
__global__ __launch_bounds__(256) void stats_partial(
    const float* __restrict__ pred, const float* __restrict__ tru,
    const float* __restrict__ orig, const float* __restrict__ feat,
    float* __restrict__ ws) {
  __shared__ float sh[14][4];
  const int blk = blockIdx.x;
  const int b = blk >> 2, q = blk & 3;
  const int tid = threadIdx.x;
  const int i = q * 256 + tid;
  const float* pb = pred + (size_t)b * NPG * 3;
  const float* tb = tru  + (size_t)b * NPG * 3;
  const float* ob = orig + (size_t)b * NPG * 3;

  float p0 = pb[i*3+0], p1 = pb[i*3+1], p2 = pb[i*3+2];
  float t0 = tb[i*3+0], t1 = tb[i*3+1], t2 = tb[i*3+2];
  float o0 = ob[i*3+0], o1 = ob[i*3+1], o2 = ob[i*3+2];
  float d0 = p0 - t0, d1 = p1 - t1, d2 = p2 - t2;
  float rec = d0*d0 + d1*d1 + d2*d2;

  float r[14];
  r[0]  = waveMin(p0); r[1]  = waveMin(p1); r[2]  = waveMin(p2);
  r[3]  = waveMax(p0); r[4]  = waveMax(p1); r[5]  = waveMax(p2);
  r[6]  = waveMin(o0); r[7]  = waveMin(o1); r[8]  = waveMin(o2);
  r[9]  = waveMax(o0); r[10] = waveMax(o1); r[11] = waveMax(o2);
  r[12] = waveSum(rec);
  r[13] = waveSum(p2);

  const int lane = tid & 63, wid = tid >> 6;
  if (lane == 0) {
#pragma unroll
    for (int k = 0; k < 14; k++) sh[k][wid] = r[k];
  }
  __syncthreads();
  if (tid == 0) {
    float* w = ws + WS_STATS + ((size_t)blk << 4);
#pragma unroll
    for (int k = 0; k < 3; k++) {
      w[k]     = fminf(fminf(sh[k][0],     sh[k][1]),     fminf(sh[k][2],     sh[k][3]));
      w[k + 3] = fmaxf(fmaxf(sh[k + 3][0], sh[k + 3][1]), fmaxf(sh[k + 3][2], sh[k + 3][3]));
      w[k + 6] = fminf(fminf(sh[k + 6][0], sh[k + 6][1]), fminf(sh[k + 6][2], sh[k + 6][3]));
      w[k + 9] = fmaxf(fmaxf(sh[k + 9][0], sh[k + 9][1]), fmaxf(sh[k + 9][2], sh[k + 9][3]));
    }
    w[12] = sh[12][0] + sh[12][1] + sh[12][2] + sh[12][3];
    w[13] = sh[13][0] + sh[13][1] + sh[13][2] + sh[13][3];
    if (q == 0) ws[WS_V + b] = feat[(size_t)b * NPG * NFEAT + (NFEAT - 3)];
  }
}

// 1024 blocks x 256 threads: block (b, s) computes the 256x256 collapse tile
// (ic=s>>2, jc=s&3); s==0 blocks additionally compute the batch's electrode
// term (oz min/max combined inline from stats partials).
__global__ __launch_bounds__(256) void coll_elec(
    const float* __restrict__ pred, const float* __restrict__ orig,
    float* __restrict__ ws) {
  __shared__ float4 pts[TT];
  __shared__ float sred[4];
  __shared__ float se[2][4];
  const int x = blockIdx.x;
  const int b = x >> 4, s = x & 15;
  const int ic = s >> 2, jc = s & 3;
  const int tid = threadIdx.x;
  const float* pb = pred + (size_t)b * NPG * 3;

  const int j = jc * TT + tid;
  pts[tid] = make_float4(pb[j*3+0], pb[j*3+1], pb[j*3+2], 0.f);
  const int i = ic * TT + tid;
  const float px = pb[i*3+0], py = pb[i*3+1], pz = pb[i*3+2];
  __syncthreads();

  float acc = 0.f;
#pragma unroll 8
  for (int k = 0; k < TT; k++) {
    float4 pj = pts[k];  // wave-uniform address: LDS broadcast, conflict-free
    float dx = px - pj.x, dy = py - pj.y, dz = pz - pj.z;
    float d2 = fmaf(dx, dx, fmaf(dy, dy, dz * dz));   // >= 0 always
    float d = FAST_SQRT(d2);
    float t = fmaxf(MIN_DIST - d, 0.f);
    acc = fmaf(t, t, acc);
  }
  // self-pair: dx=dy=dz=0 exactly -> d2=0, sqrt=0, t=MIN_DIST
  if (ic == jc) acc -= MIN_DIST * MIN_DIST;
  acc = waveSum(acc);
  if ((tid & 63) == 0) sred[tid >> 6] = acc;

  float cnt = 0.f, el = 0.f;
  if (s == 0) {
    const float* ob = orig + (size_t)b * NPG * 3;
    float ozmin = INFINITY, ozmax = -INFINITY;
#pragma unroll
    for (int qq = 0; qq < 4; qq++) {
      const float* w = ws + WS_STATS + ((size_t)(b * 4 + qq) << 4);
      ozmin = fminf(ozmin, w[8]);
      ozmax = fmaxf(ozmax, w[11]);
    }
    const float zr = ozmax - ozmin;
    const float lo = ozmin + 0.15f * zr;
    const float hi = ozmax - 0.15f * zr;
#pragma unroll
    for (int kk = 0; kk < 4; kk++) {
      const int ii = kk * 256 + tid;
      float oz = ob[ii*3+2];
      if (oz <= lo || oz >= hi) {
        float e0 = pb[ii*3+0] - ob[ii*3+0];
        float e1 = pb[ii*3+1] - ob[ii*3+1];
        float e2 = pb[ii*3+2] - oz;
        cnt += 1.f;
        el += e0*e0 + e1*e1 + e2*e2;
      }
    }
    cnt = waveSum(cnt);
    el = waveSum(el);
    if ((tid & 63) == 0) { se[0][tid >> 6] = cnt; se[1][tid >> 6] = el; }
  }
  __syncthreads();
  if (tid == 0) {
    ws[WS_COLL + x] = sred[0] + sred[1] + sred[2] + sred[3];
    if (s == 0) {
      ws[WS_CNT + b] = se[0][0] + se[0][1] + se[0][2] + se[0][3];
      ws[WS_ELE + b] = se[1][0] + se[1][1] + se[1][2] + se[1][3];
    }
  }
}

__global__ __launch_bounds__(256) void final_kernel(
    const float* __restrict__ ws, float* __restrict__ out) {
  const int tid = threadIdx.x;
  __shared__ float shc[4];

  // reduce collapse partials (1024 values over 256 threads)
  float c = 0.f;
  for (int k = tid; k < 1024; k += 256) c += ws[WS_COLL + k];
  c = waveSum(c);
  if ((tid & 63) == 0) shc[tid >> 6] = c;
  __syncthreads();

  // per-batch terms: one lane per batch on wave 0
  if (tid < 64) {
    const int bb = tid;
    float pmn0 =  INFINITY, pmn1 =  INFINITY, pmn2 =  INFINITY;
    float pmx0 = -INFINITY, pmx1 = -INFINITY, pmx2 = -INFINITY;
    float omn0 =  INFINITY, omn1 =  INFINITY, omn2 =  INFINITY;
    float omx0 = -INFINITY, omx1 = -INFINITY, omx2 = -INFINITY;
    float rec = 0.f, zs = 0.f;
#pragma unroll
    for (int q = 0; q < 4; q++) {
      const float* w = ws + WS_STATS + ((size_t)(bb * 4 + q) << 4);
      pmn0 = fminf(pmn0, w[0]);  pmn1 = fminf(pmn1, w[1]);  pmn2 = fminf(pmn2, w[2]);
      pmx0 = fmaxf(pmx0, w[3]);  pmx1 = fmaxf(pmx1, w[4]);  pmx2 = fmaxf(pmx2, w[5]);
      omn0 = fminf(omn0, w[6]);  omn1 = fminf(omn1, w[7]);  omn2 = fminf(omn2, w[8]);
      omx0 = fmaxf(omx0, w[9]);  omx1 = fmaxf(omx1, w[10]); omx2 = fmaxf(omx2, w[11]);
      rec += w[12]; zs += w[13];
    }
    float pdx = pmx0 - pmn0, pdy = pmx1 - pmn1, pdz = pmx2 - pmn2;
    float odx = omx0 - omn0, ody = omx1 - omn1, odz = omx2 - omn2;
    float rx = (pdx - odx) / (odx + 1e-8f);
    float ry = (pdy - ody) / (ody + 1e-8f);
    float rz = (pdz - odz) / (odz + 1e-8f);
    float vol = fmaxf(rx - 0.02f, 0.f) + fmaxf(ry - 0.02f, 0.f) +
                2.f * fmaxf(rz, 0.f);

    float v = ws[WS_V + bb];
    float zcom = zs * (1.f / NPG);
    float znorm = (zcom - pmn2) / (pdz + 1e-8f);
    float target = (v > 0.f) ? 0.6f : 0.4f;
    float dd = znorm - target;
    float contrib = (fabsf(v) >= 1e-6f) ? dd * dd : 0.f;

    float cnt = ws[WS_CNT + bb];
    float el  = ws[WS_ELE + bb];

    vol = waveSum(vol);
    contrib = waveSum(contrib);
    rec = waveSum(rec);
    cnt = waveSum(cnt);
    el  = waveSum(el);

    if (tid == 0) {
      float ctot = shc[0] + shc[1] + shc[2] + shc[3];
      float o_recon  = rec / (float)(NTOT * 3);
      float o_volume = vol / (float)NB;
      float o_elec   = el / (cnt * 3.f);
      float o_coll   = ctot / ((float)NB * NPG * (NPG - 1));
      float o_field  = contrib / (float)NB;
      float total = 1.0f * o_recon + 10.0f * o_volume + 50.0f * o_elec +
                    5.0f * o_coll + 2.0f * o_field;
      out[0] = total;
      out[1] = o_recon;
      out[2] = o_volume;
      out[3] = o_elec;
      out[4] = o_coll;
      out[5] = o_field;
    }
  }
}

extern "C" void kernel_launch(void* const* d_in, const int* in_sizes, int n_in,
                              void* d_out, int out_size, void* d_ws, size_t ws_size,
                              hipStream_t stream) {
  const float* pred = (const float*)d_in[0];
  const float* tru  = (const float*)d_in[1];
  const float* orig = (const float*)d_in[2];
  const float* feat = (const float*)d_in[3];
  float* ws  = (float*)d_ws;
  float* out = (float*)d_out;

  stats_partial<<<256, 256, 0, stream>>>(pred, tru, orig, feat, ws);
  coll_elec<<<1024, 256, 0, stream>>>(pred, orig, ws);
  final_kernel<<<1, 256, 0, stream>>>(ws, out);
}

// Round 6
// 83.435 us; speedup vs baseline: 2.2661x; 1.0860x over previous
//
#include <hip/hip_runtime.h>
#include <math.h>

#define NB 64
#define NPG 1024
#define NFEAT 8
#define NTOT (NB * NPG)
#define TT 128                  // collapse tile edge
#define NTILE 36                // upper-triangular 8x8 tile pairs
#define NBLK (NB * NTILE)       // 2304 blocks

static constexpr float MIN_DIST = 2.9f;

#if __has_builtin(__builtin_amdgcn_sqrtf)
#define FAST_SQRT(x) __builtin_amdgcn_sqrtf(x)   // raw v_sqrt_f32, ~1 ulp
#else
#define FAST_SQRT(x) sqrtf(x)
#endif

// ws float layout (every slot written before read; no zero-init needed):
//   WS_STATS + b*16 + q : final per-batch stats, q:
//        0..2 pmin, 3..5 pmax, 6..8 omin, 9..11 omax, 12 recon, 13 zpsum
//   WS_V   + b : node_features v per batch
//   WS_CNT + b : electrode count per batch
//   WS_ELE + b : electrode sum per batch
//   WS_COLL + x : weighted collapse partial per block x (x < NBLK)
// total 3520 floats = 14.1 KB
#define WS_STATS 0
#define WS_V     1024
#define WS_CNT   1088
#define WS_ELE   1152
#define WS_COLL  1216

// (ic,jc) for tile index s in [0,36): all pairs with ic <= jc
__constant__ unsigned char ICT[NTILE] = {
    0,0,0,0,0,0,0,0, 1,1,1,1,1,1,1, 2,2,2,2,2,2,
    3,3,3,3,3, 4,4,4,4, 5,5,5, 6,6, 7};
__constant__ unsigned char JCT[NTILE] = {
    0,1,2,3,4,5,6,7, 1,2,3,4,5,6,7, 2,3,4,5,6,7,
    3,4,5,6,7, 4,5,6,7, 5,6,7, 6,7, 7};

__device__ __forceinline__ float waveSum(float v) {
#pragma unroll
  for (int o = 32; o > 0; o >>= 1) v += __shfl_down(v, o, 64);
  return v;
}
__device__ __forceinline__ float waveMin(float v) {
#pragma unroll
  for (int o = 32; o > 0; o >>= 1) v = fminf(v, __shfl_down(v, o, 64));
  return v;
}
__device__ __forceinline__ float waveMax(float v) {
#pragma unroll
  for (int o = 32; o > 0; o >>= 1) v = fmaxf(v, __shfl_down(v, o, 64));
  return v;
}

// 2304 blocks x 128 threads. Block (b, s): collapse tile (ic<=jc), off-diag
// weighted x2 by symmetry (t(i,j)^2 == t(j,i)^2 bit-exactly). s==0 blocks
// additionally compute the whole batch's stats + electrode term.
__global__ __launch_bounds__(128) void main_kernel(
    const float* __restrict__ pred, const float* __restrict__ tru,
    const float* __restrict__ orig, const float* __restrict__ feat,
    float* __restrict__ ws) {
  __shared__ float4 pts[TT];
  __shared__ float scoll[2];
  __shared__ float sst[16][2];
  const int x = blockIdx.x;
  const int b = x / NTILE;
  const int s = x - b * NTILE;
  const int ic = ICT[s], jc = JCT[s];
  const int tid = threadIdx.x;
  const int wid = tid >> 6, lane = tid & 63;
  const float* pb = pred + (size_t)b * NPG * 3;

  // ---- collapse tile ----
  {
    const int j = jc * TT + tid;
    pts[tid] = make_float4(pb[j*3+0], pb[j*3+1], pb[j*3+2], 0.f);
  }
  const int i = ic * TT + tid;
  const float px = pb[i*3+0], py = pb[i*3+1], pz = pb[i*3+2];
  __syncthreads();

  float acc = 0.f;
#pragma unroll 8
  for (int k = 0; k < TT; k++) {
    float4 pj = pts[k];  // wave-uniform address: LDS broadcast, conflict-free
    float dx = px - pj.x, dy = py - pj.y, dz = pz - pj.z;
    float d2 = fmaf(dx, dx, fmaf(dy, dy, dz * dz));   // >= 0 always
    float d = FAST_SQRT(d2);
    float t = fmaxf(MIN_DIST - d, 0.f);
    acc = fmaf(t, t, acc);
  }
  if (ic == jc) acc -= MIN_DIST * MIN_DIST;  // self-pair: d2==0 exactly
  else          acc += acc;                  // symmetric double-count
  acc = waveSum(acc);
  if (lane == 0) scoll[wid] = acc;
  __syncthreads();
  if (tid == 0) ws[WS_COLL + x] = scoll[0] + scoll[1];

  // ---- per-batch stats + electrode (one block per batch) ----
  if (s == 0) {
    const float* tb = tru  + (size_t)b * NPG * 3;
    const float* ob = orig + (size_t)b * NPG * 3;
    float pmn0 =  INFINITY, pmn1 =  INFINITY, pmn2 =  INFINITY;
    float pmx0 = -INFINITY, pmx1 = -INFINITY, pmx2 = -INFINITY;
    float omn0 =  INFINITY, omn1 =  INFINITY, omn2 =  INFINITY;
    float omx0 = -INFINITY, omx1 = -INFINITY, omx2 = -INFINITY;
    float rec = 0.f, zps = 0.f;
    for (int k = 0; k < 8; k++) {
      const int ii = k * TT + tid;
      float p0 = pb[ii*3+0], p1 = pb[ii*3+1], p2 = pb[ii*3+2];
      float t0 = tb[ii*3+0], t1 = tb[ii*3+1], t2 = tb[ii*3+2];
      float o0 = ob[ii*3+0], o1 = ob[ii*3+1], o2 = ob[ii*3+2];
      pmn0 = fminf(pmn0, p0); pmx0 = fmaxf(pmx0, p0);
      pmn1 = fminf(pmn1, p1); pmx1 = fmaxf(pmx1, p1);
      pmn2 = fminf(pmn2, p2); pmx2 = fmaxf(pmx2, p2);
      omn0 = fminf(omn0, o0); omx0 = fmaxf(omx0, o0);
      omn1 = fminf(omn1, o1); omx1 = fmaxf(omx1, o1);
      omn2 = fminf(omn2, o2); omx2 = fmaxf(omx2, o2);
      float d0 = p0 - t0, d1 = p1 - t1, d2 = p2 - t2;
      rec += d0*d0 + d1*d1 + d2*d2;
      zps += p2;
    }
    float r[14];
    r[0]  = waveMin(pmn0); r[1]  = waveMin(pmn1); r[2]  = waveMin(pmn2);
    r[3]  = waveMax(pmx0); r[4]  = waveMax(pmx1); r[5]  = waveMax(pmx2);
    r[6]  = waveMin(omn0); r[7]  = waveMin(omn1); r[8]  = waveMin(omn2);
    r[9]  = waveMax(omx0); r[10] = waveMax(omx1); r[11] = waveMax(omx2);
    r[12] = waveSum(rec);
    r[13] = waveSum(zps);
    if (lane == 0) {
#pragma unroll
      for (int q = 0; q < 14; q++) sst[q][wid] = r[q];
    }
    __syncthreads();
    if (tid == 0) {
      float* w = ws + WS_STATS + ((size_t)b << 4);
      float c[14];
#pragma unroll
      for (int q = 0; q < 3; q++) {
        c[q]     = fminf(sst[q][0],     sst[q][1]);
        c[q + 3] = fmaxf(sst[q + 3][0], sst[q + 3][1]);
        c[q + 6] = fminf(sst[q + 6][0], sst[q + 6][1]);
        c[q + 9] = fmaxf(sst[q + 9][0], sst[q + 9][1]);
      }
      c[12] = sst[12][0] + sst[12][1];
      c[13] = sst[13][0] + sst[13][1];
#pragma unroll
      for (int q = 0; q < 14; q++) w[q] = c[q];
      float zr = c[11] - c[8];
      sst[14][0] = c[8]  + 0.15f * zr;   // lo
      sst[15][0] = c[11] - 0.15f * zr;   // hi
      ws[WS_V + b] = feat[(size_t)b * NPG * NFEAT + (NFEAT - 3)];
    }
    __syncthreads();
    const float lo = sst[14][0], hi = sst[15][0];
    float cnt = 0.f, el = 0.f;
    for (int k = 0; k < 8; k++) {
      const int ii = k * TT + tid;
      float oz = ob[ii*3+2];
      if (oz <= lo || oz >= hi) {
        float e0 = pb[ii*3+0] - ob[ii*3+0];
        float e1 = pb[ii*3+1] - ob[ii*3+1];
        float e2 = pb[ii*3+2] - oz;
        cnt += 1.f;
        el += e0*e0 + e1*e1 + e2*e2;
      }
    }
    cnt = waveSum(cnt);
    el  = waveSum(el);
    if (lane == 0) { sst[0][wid] = cnt; sst[1][wid] = el; }
    __syncthreads();
    if (tid == 0) {
      ws[WS_CNT + b] = sst[0][0] + sst[0][1];
      ws[WS_ELE + b] = sst[1][0] + sst[1][1];
    }
  }
}

__global__ __launch_bounds__(256) void final_kernel(
    const float* __restrict__ ws, float* __restrict__ out) {
  const int tid = threadIdx.x;
  __shared__ float shc[4];

  // reduce collapse partials (2304 values over 256 threads)
  float c = 0.f;
  for (int k = tid; k < NBLK; k += 256) c += ws[WS_COLL + k];
  c = waveSum(c);
  if ((tid & 63) == 0) shc[tid >> 6] = c;
  __syncthreads();

  // per-batch terms: one lane per batch on wave 0
  if (tid < 64) {
    const float* w = ws + WS_STATS + ((size_t)tid << 4);
    float pmn2 = w[2];
    float pdx = w[3] - w[0], pdy = w[4] - w[1], pdz = w[5] - w[2];
    float odx = w[9] - w[6], ody = w[10] - w[7], odz = w[11] - w[8];
    float rec = w[12], zs = w[13];

    float rx = (pdx - odx) / (odx + 1e-8f);
    float ry = (pdy - ody) / (ody + 1e-8f);
    float rz = (pdz - odz) / (odz + 1e-8f);
    float vol = fmaxf(rx - 0.02f, 0.f) + fmaxf(ry - 0.02f, 0.f) +
                2.f * fmaxf(rz, 0.f);

    float v = ws[WS_V + tid];
    float zcom = zs * (1.f / NPG);
    float znorm = (zcom - pmn2) / (pdz + 1e-8f);
    float target = (v > 0.f) ? 0.6f : 0.4f;
    float dd = znorm - target;
    float contrib = (fabsf(v) >= 1e-6f) ? dd * dd : 0.f;

    float cnt = ws[WS_CNT + tid];
    float el  = ws[WS_ELE + tid];

    vol = waveSum(vol);
    contrib = waveSum(contrib);
    rec = waveSum(rec);
    cnt = waveSum(cnt);
    el  = waveSum(el);

    if (tid == 0) {
      float ctot = shc[0] + shc[1] + shc[2] + shc[3];
      float o_recon  = rec / (float)(NTOT * 3);
      float o_volume = vol / (float)NB;
      float o_elec   = el / (cnt * 3.f);
      float o_coll   = ctot / ((float)NB * NPG * (NPG - 1));
      float o_field  = contrib / (float)NB;
      float total = 1.0f * o_recon + 10.0f * o_volume + 50.0f * o_elec +
                    5.0f * o_coll + 2.0f * o_field;
      out[0] = total;
      out[1] = o_recon;
      out[2] = o_volume;
      out[3] = o_elec;
      out[4] = o_coll;
      out[5] = o_field;
    }
  }
}

extern "C" void kernel_launch(void* const* d_in, const int* in_sizes, int n_in,
                              void* d_out, int out_size, void* d_ws, size_t ws_size,
                              hipStream_t stream) {
  const float* pred = (const float*)d_in[0];
  const float* tru  = (const float*)d_in[1];
  const float* orig = (const float*)d_in[2];
  const float* feat = (const float*)d_in[3];
  float* ws  = (float*)d_ws;
  float* out = (float*)d_out;

  main_kernel<<<NBLK, 128, 0, stream>>>(pred, tru, orig, feat, ws);
  final_kernel<<<1, 256, 0, stream>>>(ws, out);
}